// Round 16
// baseline (383.366 us; speedup 1.0000x reference)
//
#include <hip/hip_runtime.h>
#include <hip/hip_fp16.h>

#define NB   128
#define NPOS 131072   // 128*32*32
#define NBIN 256      // packed bins: plane 0 holds (bin0, bin256)
#define PI_F 3.14159265358979323846f

typedef _Float16 f16;
typedef f16   f16x4 __attribute__((ext_vector_type(4)));
typedef f16   f16x8 __attribute__((ext_vector_type(8)));
typedef float f32x4 __attribute__((ext_vector_type(4)));

// ---------------------------------------------------------------------------
// kA: build the real-DFT matrix A[512][512] f16 once into workspace.
// Row 2k = cos(2*pi*k*n/512); row 2k+1 = -sin(...); row 1 (the Im X0 = 0
// slot) is repurposed as (-1)^n so C-row 1 = X256 (plane-0 packing).
// ---------------------------------------------------------------------------
__global__ __launch_bounds__(512) void kA_build(f16* __restrict__ A) {
    const int m = blockIdx.x, n = threadIdx.x;
    const int k  = m >> 1;
    const int ph = (k * n) & 511;
    const float ang = (float)ph * (PI_F / 256.0f);
    float v;
    if (m == 1)     v = (n & 1) ? -1.0f : 1.0f;
    else if (m & 1) v = -__sinf(ang);
    else            v = __cosf(ang);
    A[m * 512 + n] = (f16)v;
}

// ---------------------------------------------------------------------------
// K1 (MFMA): H = tf .* (A @ env) via f16 GEMM, M=512 (rows 2k/2k+1 = Re/Im
// X_k), K=512 (samples), N=131072 (positions). Block: 512 thr = 8 waves,
// BN=64 positions, full M per block (so nz is read exactly once), BK=32,
// 16 K-steps. Wave w owns M-rows [64w,64w+64): 4x4 frags of 16x16x32.
// A-frags read straight from global (512KB matrix, L2-resident; quarter-wave
// groups cover full 64B lines). B-tile = env*512 f16 built inline in LDS
// from nz + imp-lerp (clip == identity, established r8).
// Epilogue: lane's acc regs (0,1)=(Re,Im) of plane K0, (2,3) of K0+1 ->
// direct __half2 stores, 16 lanes = 64B line per plane. No LDS transpose.
// k-mapping errors in frag layout cancel (same mapping used for A and B).
// r14 post-mortem fix: __syncthreads() after ldsImp staging — the s=0 env
// build read imp knots staged by OTHER waves with no barrier (race; 84%-
// scale garbage). One barrier, nothing else changed.
// Spill guard: WRITE_SIZE must stay ~131072 KB.
// ---------------------------------------------------------------------------
__global__ __launch_bounds__(512) void k1_gemm(
    const float* __restrict__ tf,    // [NPOS][257]
    const float* __restrict__ imp,   // [NPOS][16]
    const float* __restrict__ nz,    // [NPOS][512]
    const f16*   __restrict__ A,     // [512][512]
    __half2*     __restrict__ Hbuf)  // [NBIN][NPOS]
{
    __shared__ f16   Bt[64][40];     // [pos][k-in-step], pad 32->40 (banks)
    __shared__ float ldsImp[64][16];

    const int tid  = threadIdx.x;
    const int wv   = tid >> 6;       // 0..7
    const int lane = tid & 63;
    const int h    = lane >> 4;      // quarter-wave 0..3
    const int r    = lane & 15;
    const int pos0 = blockIdx.x << 6;    // 64 positions/block

    ((float*)ldsImp)[tid]       = imp[(size_t)pos0 * 16 + tid];
    ((float*)ldsImp)[tid + 512] = imp[(size_t)pos0 * 16 + 512 + tid];
    __syncthreads();                 // r14 FIX: imp staged by all waves

    // B-staging role: this thread fills pos sp, samples n0..n0+3 each step
    const int sp  = tid >> 3;
    const int ns0 = (tid & 7) << 2;
    const size_t nzrow = (size_t)(pos0 + sp) * 512;

    f32x4 acc[4][4];
    #pragma unroll
    for (int i = 0; i < 4; ++i)
        #pragma unroll
        for (int j = 0; j < 4; ++j)
            acc[i][j] = (f32x4)(0.0f);

    const int mbase = wv << 6;

    for (int s = 0; s < 16; ++s) {
        // ----- build this thread's 4 env values (no Bt access yet) -----
        const int n0 = (s << 5) + ns0;
        float4 nv4 = *(const float4*)(nz + nzrow + n0);
        float nvv[4] = {nv4.x, nv4.y, nv4.z, nv4.w};
        f16x4 bv;
        #pragma unroll
        for (int u = 0; u < 4; ++u) {
            float t = (float)(n0 + u);
            float p = (t - 15.5f) * (1.0f / 32.0f);
            p = fminf(fmaxf(p, 0.0f), 15.0f);
            int j0 = (int)p; j0 = j0 > 14 ? 14 : j0;
            float fr = p - (float)j0;
            float a  = ldsImp[sp][j0], b = ldsImp[sp][j0 + 1];
            float e  = fmaf(fr, b - a, a) * nvv[u] * 512.0f;  // scale->f16 range
            bv[u] = (f16)e;
        }
        __syncthreads();                       // prev step's Bt reads done
        *(f16x4*)&Bt[sp][ns0] = bv;
        __syncthreads();                       // Bt ready

        // ----- A frags from global (L2-hot): row = mbase+mf*16+r,
        //       k elems = 4h+{0..3} and 16+4h+{0..3} (same mapping as B) ----
        const f16* ap = A + (size_t)(mbase + r) * 512 + (s << 5) + (h << 2);
        f16x8 af[4];
        #pragma unroll
        for (int mf = 0; mf < 4; ++mf) {
            f16x4 lo = *(const f16x4*)(ap + ((mf << 4) * 512));
            f16x4 hi = *(const f16x4*)(ap + ((mf << 4) * 512) + 16);
            af[mf] = __builtin_shufflevector(lo, hi, 0, 1, 2, 3, 4, 5, 6, 7);
        }
        // ----- B frags from LDS: col(pos) = nf*16+r, same k mapping -----
        f16x8 bf[4];
        #pragma unroll
        for (int nf = 0; nf < 4; ++nf) {
            f16x4 lo = *(const f16x4*)&Bt[(nf << 4) + r][h << 2];
            f16x4 hi = *(const f16x4*)&Bt[(nf << 4) + r][16 + (h << 2)];
            bf[nf] = __builtin_shufflevector(lo, hi, 0, 1, 2, 3, 4, 5, 6, 7);
        }
        // ----- 16 MFMA: 4x4 outer product -----
        #pragma unroll
        for (int mf = 0; mf < 4; ++mf)
            #pragma unroll
            for (int nf = 0; nf < 4; ++nf)
                acc[mf][nf] = __builtin_amdgcn_mfma_f32_16x16x32_f16(
                    af[mf], bf[nf], acc[mf][nf], 0, 0, 0);
    }

    // ----- epilogue: acc regs (0,1) = (Re,Im) plane K0; (2,3) plane K0+1.
    // C layout (m89-verified): col = lane&15 (pos), row = (lane>>4)*4 + reg.
    const float is = 1.0f / 512.0f;     // undo env*512
    #pragma unroll
    for (int mf = 0; mf < 4; ++mf) {
        const int K0 = (wv << 5) + (mf << 3) + (h << 1);   // even, 0..254
        #pragma unroll
        for (int nf = 0; nf < 4; ++nf) {
            const int pos = pos0 + (nf << 4) + r;
            const float* tfp = tf + (size_t)pos * 257;
            float t0 = tfp[K0] * is;
            float t1 = tfp[K0 + 1] * is;
            float tb = (K0 == 0) ? tfp[256] * is : t0;  // plane0.y = tf256*X256
            f32x4 a = acc[mf][nf];
            Hbuf[(size_t)K0 * NPOS + pos] =
                __floats2half2_rn(t0 * a[0], tb * a[1]);
            Hbuf[(size_t)(K0 + 1) * NPOS + pos] =
                __floats2half2_rn(t1 * a[2], t1 * a[3]);
        }
    }
}

// ---------------------------------------------------------------------------
// K2: frequency-domain scan. Block k owns bin-plane k: 32x32 complex state.
// ---------------------------------------------------------------------------
__global__ __launch_bounds__(1024) void k2_scan(
    const __half2* __restrict__ Hbuf,  // [NBIN][NPOS]
    float2* __restrict__ Mbuf)         // [NB][NBIN]
{
    __shared__ float2 sfb[2][32][33];
    const int k   = blockIdx.x;
    const int tid = threadIdx.x;
    const int h   = tid >> 5, w = tid & 31;
    const int hm = (h == 0) ? 1 : h - 1, hp = (h == 31) ? 30 : h + 1;
    const int wm = (w == 0) ? 1 : w - 1, wp = (w == 31) ? 30 : w + 1;

    const __half2* Hp = Hbuf + (size_t)k * NPOS + tid;
    __half2 c0 = Hp[0];
    __half2 c1 = Hp[1024];
    float fr = 0.0f, fi = 0.0f;

    for (int b = 0; b < NB; ++b) {
        float2 hv = __half22float2(c0);
        c0 = c1;
        if (b + 2 < NB) c1 = Hp[(size_t)(b + 2) << 10];
        fr += hv.x; fi += hv.y;
        if (tid == 528) Mbuf[b * NBIN + k] = make_float2(fr, fi); // mic BEFORE box
        sfb[b & 1][h][w] = make_float2(fr, fi);
        __syncthreads();
        float sr = 0.0f, si = 0.0f; float2 v;
        v = sfb[b & 1][hm][wm]; sr += v.x; si += v.y;
        v = sfb[b & 1][hm][w ]; sr += v.x; si += v.y;
        v = sfb[b & 1][hm][wp]; sr += v.x; si += v.y;
        v = sfb[b & 1][h ][wm]; sr += v.x; si += v.y;
        v = sfb[b & 1][h ][w ]; sr += v.x; si += v.y;
        v = sfb[b & 1][h ][wp]; sr += v.x; si += v.y;
        v = sfb[b & 1][hp][wm]; sr += v.x; si += v.y;
        v = sfb[b & 1][hp][w ]; sr += v.x; si += v.y;
        v = sfb[b & 1][hp][wp]; sr += v.x; si += v.y;
        fr = sr * (1.0f / 9.0f); fi = si * (1.0f / 9.0f);
    }
}

// ---------------------------------------------------------------------------
// K3: per-block-b inverse rDFT (512 samples from 257 Hermitian bins, 1/512).
// ---------------------------------------------------------------------------
__global__ __launch_bounds__(512) void k3_idft(
    const float2* __restrict__ Mbuf,
    float* __restrict__ out)
{
    __shared__ float2 lm[256];
    const int b = blockIdx.x;
    const int t = threadIdx.x;
    if (t < 256) lm[t] = Mbuf[b * NBIN + t];
    __syncthreads();
    float acc = 0.0f;
    #pragma unroll 4
    for (int k = 1; k < 256; ++k) {
        int   ph  = (k * t) & 511;
        float ang = (float)ph * (PI_F / 256.0f);
        float sv, cv; __sincosf(ang, &sv, &cv);
        float2 m = lm[k];
        acc += m.x * cv - m.y * sv;
    }
    float m0 = lm[0].x, m256 = lm[0].y;
    float r  = m0 + ((t & 1) ? -m256 : m256) + 2.0f * acc;
    out[(b << 9) + t] = r * (1.0f / 512.0f);
}

extern "C" void kernel_launch(void* const* d_in, const int* in_sizes, int n_in,
                              void* d_out, int out_size, void* d_ws, size_t ws_size,
                              hipStream_t stream)
{
    const float* tf  = (const float*)d_in[1]; // (128,32,32,257)
    const float* imp = (const float*)d_in[2]; // (128,32,32,16)
    const float* nz  = (const float*)d_in[3]; // (128,32,32,512)
    float* out = (float*)d_out;

    const size_t hbytes = (size_t)NBIN * NPOS * sizeof(__half2);  // 134.2 MB
    const size_t mbytes = (size_t)NB * NBIN * sizeof(float2);     // 256 KB
    const size_t abytes = (size_t)512 * 512 * sizeof(f16);        // 512 KB
    if (ws_size < hbytes + mbytes + abytes) {
        (void)hipMemsetAsync(d_out, 0xFF, (size_t)out_size * sizeof(float), stream);
        return;
    }
    __half2* Hbuf = (__half2*)d_ws;
    float2*  Mbuf = (float2*)((char*)d_ws + hbytes);
    f16*     Amat = (f16*)((char*)d_ws + hbytes + mbytes);

    kA_build<<<512, 512, 0, stream>>>(Amat);
    k1_gemm<<<NPOS / 64, 512, 0, stream>>>(tf, imp, nz, Amat, Hbuf);
    k2_scan<<<NBIN, 1024, 0, stream>>>(Hbuf, Mbuf);
    k3_idft<<<NB, 512, 0, stream>>>(Mbuf, out);
}